// Round 1
// 782.585 us; speedup vs baseline: 1.0627x; 1.0627x over previous
//
#include <hip/hip_runtime.h>
#include <math.h>

#define CIN   96
#define HW_IN 3969     // 63*63
#define WIN   63
#define COUT  256
#define NPIX  900      // 30*30
#define WO    30
#define KTOT  2400     // CIN*5*5
#define NB    128
#define KSTEPS 75      // KTOT/32
#define AGG_OFF 65536
#define AGG_BYTES ((size_t)NB * 2 * KSTEPS * 8192)   // 157,286,400 B

typedef short bf16x8 __attribute__((ext_vector_type(8)));
typedef float f32x4  __attribute__((ext_vector_type(4)));
typedef __attribute__((address_space(1))) const void gas_t;
typedef __attribute__((address_space(3))) void las_t;

// hardware packed f32->bf16 (RNE), 2 values per instruction
__device__ __forceinline__ unsigned pk2(float lo, float hi) {
  unsigned r;
  asm("v_cvt_pk_bf16_f32 %0, %1, %2" : "=v"(r) : "v"(lo), "v"(hi));
  return r;
}

// ---- Stage 1: per-(b,ci) global average pool over 63x63 ----
__global__ __launch_bounds__(256) void pool_kernel(const float* __restrict__ x,
                                                   float* __restrict__ pooled) {
  const int ci = blockIdx.x;
  const int b  = blockIdx.y;
  const float* xc = x + ((size_t)b * CIN + ci) * HW_IN;
  const int tid = threadIdx.x, lane = tid & 63, wv = tid >> 6;
  float s = 0.f;
  const int head = (4 - (ci & 3)) & 3;
  if (tid < head) s += xc[tid];
  const float4* x4 = (const float4*)(xc + head);
  const int n4 = (HW_IN - head) >> 2;
  for (int i = tid; i < n4; i += 256) { float4 v = x4[i]; s += (v.x + v.y) + (v.z + v.w); }
  const int done = head + (n4 << 2);
  if (tid < HW_IN - done) s += xc[done + tid];
  #pragma unroll
  for (int off = 32; off > 0; off >>= 1) s += __shfl_xor(s, off, 64);
  __shared__ float part[4];
  if (lane == 0) part[wv] = s;
  __syncthreads();
  if (tid == 0)
    pooled[(size_t)b * CIN + ci] = (part[0] + part[1] + part[2] + part[3]) * (1.0f / HW_IN);
}

// ---- Stage 2: attention MLP + softmax(logits / 31) ----
__global__ __launch_bounds__(64) void attn_kernel(const float* __restrict__ pooled,
                                                  const float* __restrict__ w1,
                                                  const float* __restrict__ w2,
                                                  float* __restrict__ att) {
  const int b = blockIdx.x;
  const int tid = threadIdx.x;
  __shared__ float hidden[24];
  const float* pb = pooled + (size_t)b * CIN;
  if (tid < 24) {
    float h = 0.f;
    const float* w1r = w1 + tid * CIN;
    for (int ci = 0; ci < CIN; ++ci) h += pb[ci] * w1r[ci];
    hidden[tid] = fmaxf(h, 0.f);
  }
  __syncthreads();
  if (tid == 0) {
    float l0 = 0.f, l1 = 0.f;
    for (int j = 0; j < 24; ++j) { l0 += hidden[j] * w2[j]; l1 += hidden[j] * w2[24 + j]; }
    l0 *= (1.0f / 31.0f); l1 *= (1.0f / 31.0f);
    const float m = fmaxf(l0, l1);
    const float e0 = expf(l0 - m), e1 = expf(l1 - m);
    const float inv = 1.0f / (e0 + e1);
    att[b * 2 + 0] = e0 * inv;
    att[b * 2 + 1] = e1 * inv;
  }
}

// ---- Stage 2.5: precompute per-sample aggregated bf16 weights ----
// Layout (matches conv's global_load_lds image exactly):
//   tile (b, t, ks) = contiguous 8192 B = [row 0..127][slot 0..3] 16B units.
//   unit (row, slot) = bf16x8 of A[t*128+row][ks*32 + 8*(slot ^ ((row>>1)&3)) + 0..7]
//   (slot XOR-swizzle makes the conv's ds_read_b128 fragment reads 2-way instead of 8-way)
__global__ __launch_bounds__(256) void agg_kernel(const float* __restrict__ wc,
                                                  const float* __restrict__ we,
                                                  const float* __restrict__ att,
                                                  unsigned* __restrict__ aggW) {
  const int ks = blockIdx.x;   // 75
  const int t  = blockIdx.y;   // 2
  const int b  = blockIdx.z;   // 128
  const float a0 = att[b * 2 + 0];
  const float a1 = att[b * 2 + 1];
  unsigned* dst = aggW + ((size_t)((b * 2 + t) * KSTEPS + ks) << 11);  // 2048 dwords/tile
  #pragma unroll
  for (int uu = 0; uu < 2; ++uu) {
    const int u = threadIdx.x + uu * 256;          // 0..511 (16B units)
    const int row = u >> 2, slot = u & 3;
    const int oct = slot ^ ((row >> 1) & 3);
    const float* pc = wc + (size_t)(t * 128 + row) * KTOT + ks * 32 + oct * 8;
    const float* pe = we + (size_t)(t * 128 + row) * KTOT + ks * 32 + oct * 8;
    float4 c0 = ((const float4*)pc)[0], c1 = ((const float4*)pc)[1];
    float4 e0 = ((const float4*)pe)[0], e1 = ((const float4*)pe)[1];
    uint4 q;
    q.x = pk2(a0 * c0.x + a1 * e0.x, a0 * c0.y + a1 * e0.y);
    q.y = pk2(a0 * c0.z + a1 * e0.z, a0 * c0.w + a1 * e0.w);
    q.z = pk2(a0 * c1.x + a1 * e1.x, a0 * c1.y + a1 * e1.y);
    q.w = pk2(a0 * c1.z + a1 * e1.z, a0 * c1.w + a1 * e1.w);
    ((uint4*)dst)[u] = q;
  }
}

// ---- Stage 3: per-sample conv as implicit GEMM (bf16 MFMA 16x16x32) ----
template<bool PRE>
__global__ __launch_bounds__(256) void conv_kernel(
    const float* __restrict__ x,
    const float* __restrict__ wc, const float* __restrict__ we,
    const float* __restrict__ bc, const float* __restrict__ be,
    const float* __restrict__ att, const unsigned* __restrict__ aggW,
    float* __restrict__ out) {
  // bijective XCD swizzle over 2048 workgroups (8 XCDs, 256/chunk):
  // sibling pixel-tiles of one sample land on the same XCD -> L2 reuse of x and aggW
  const int flat = (int)(blockIdx.x + (blockIdx.y << 3) + (blockIdx.z << 4));
  const int wg   = ((flat & 7) << 8) | (flat >> 3);
  const int p0 = (wg & 7) * 128;          // pixel tile
  const int m0 = ((wg >> 3) & 1) * 128;   // Cout tile
  const int b  = wg >> 4;                 // sample

  __shared__ short As[PRE ? 128 * 32 : 128 * 40];  // PRE: linear [128][32] for global_load_lds
  __shared__ short Bs[128][40];                    // [n][k], +8 pad
  __shared__ int   koffAll[KTOT];
  __shared__ float biasS[128];

  const int tid  = threadIdx.x;
  const int wv   = tid >> 6, lane = tid & 63;
  const int quad = lane >> 4, lm = lane & 15;
  const int wm = (wv >> 1) * 64;
  const int wn = (wv & 1) * 64;

  const float a0 = att[b * 2 + 0];
  const float a1 = att[b * 2 + 1];

  if (tid < 128) biasS[tid] = a0 * bc[m0 + tid] + a1 * be[m0 + tid];
  for (int k = tid; k < KTOT; k += 256) {
    const int ci = k / 25, r = k - ci * 25;
    const int kh = r / 5,  kw = r - kh * 5;
    koffAll[k] = ci * HW_IN + kh * WIN + kw;
  }

  const int rowT = tid >> 2;
  const int oct  = (tid & 3) * 8;

  const float* xb = x + (size_t)b * (CIN * HW_IN);
  const int pA = p0 + rowT, pB = p0 + rowT + 64;
  const int ohA = pA / WO, owA = pA - ohA * WO;
  const int ohB = pB / WO, owB = pB - ohB * WO;
  const bool vA = pA < NPIX, vB = pB < NPIX;
  const float* xpA = xb + (ohA * 2) * WIN + owA * 2;
  const float* xpB = xb + (ohB * 2) * WIN + owB * 2;

  const float* wcr0 = wc + (size_t)(m0 + rowT) * KTOT + oct;  // fallback only
  const float* wer0 = we + (size_t)(m0 + rowT) * KTOT + oct;

  // PRE: per-lane global source for direct-to-LDS staging of the A tile
  const char* aggB = (const char*)aggW
                   + ((size_t)((b * 2 + (m0 >> 7)) * KSTEPS) << 13)
                   + (((wv << 7) + lane) << 4);
  const int xoct = quad ^ ((lm >> 1) & 3);   // un-swizzle for fragment reads

  const f32x4 zero = {0.f, 0.f, 0.f, 0.f};
  f32x4 acc[4][4];
  #pragma unroll
  for (int i = 0; i < 4; ++i)
    #pragma unroll
    for (int j = 0; j < 4; ++j) acc[i][j] = zero;

  for (int ks = 0; ks < KSTEPS; ++ks) {
    const int k0 = ks * 32;
    __syncthreads();
    // -- A tile --
    if constexpr (PRE) {
      // async global->LDS, no VGPR round-trip, no VALU: 2x dwordx4 per wave
      const char* src = aggB + ((size_t)ks << 13);
      __builtin_amdgcn_global_load_lds((gas_t*)src,
          (las_t*)&As[wv << 10], 16, 0, 0);
      __builtin_amdgcn_global_load_lds((gas_t*)(src + 1024),
          (las_t*)&As[(wv << 10) + 512], 16, 0, 0);
    } else {
      #pragma unroll
      for (int t = 0; t < 2; ++t) {
        const float4* pc = (const float4*)(wcr0 + (size_t)t * 64 * KTOT + k0);
        const float4* pe = (const float4*)(wer0 + (size_t)t * 64 * KTOT + k0);
        float4 c0 = pc[0], c1 = pc[1];
        float4 e0 = pe[0], e1 = pe[1];
        uint4 q;
        q.x = pk2(a0 * c0.x + a1 * e0.x, a0 * c0.y + a1 * e0.y);
        q.y = pk2(a0 * c0.z + a1 * e0.z, a0 * c0.w + a1 * e0.w);
        q.z = pk2(a0 * c1.x + a1 * e1.x, a0 * c1.y + a1 * e1.y);
        q.w = pk2(a0 * c1.z + a1 * e1.z, a0 * c1.w + a1 * e1.w);
        *(uint4*)&As[(rowT + t * 64) * 40 + oct] = q;
      }
    }
    // -- B tile: im2col gather + packed cvt --
    const int4 ka = *(const int4*)&koffAll[k0 + oct];
    const int4 kb = *(const int4*)&koffAll[k0 + oct + 4];
    {
      uint4 q = {0u, 0u, 0u, 0u};
      if (vA) {
        q.x = pk2(xpA[ka.x], xpA[ka.y]);
        q.y = pk2(xpA[ka.z], xpA[ka.w]);
        q.z = pk2(xpA[kb.x], xpA[kb.y]);
        q.w = pk2(xpA[kb.z], xpA[kb.w]);
      }
      *(uint4*)&Bs[rowT][oct] = q;
    }
    {
      uint4 q = {0u, 0u, 0u, 0u};
      if (vB) {
        q.x = pk2(xpB[ka.x], xpB[ka.y]);
        q.y = pk2(xpB[ka.z], xpB[ka.w]);
        q.z = pk2(xpB[kb.x], xpB[kb.y]);
        q.w = pk2(xpB[kb.z], xpB[kb.w]);
      }
      *(uint4*)&Bs[rowT + 64][oct] = q;
    }
    __syncthreads();
    // -- fragments + MFMA --
    bf16x8 af[4], bfv[4];
    if constexpr (PRE) {
      #pragma unroll
      for (int i = 0; i < 4; ++i)
        af[i] = *(const bf16x8*)&As[(wm + i * 16 + lm) * 32 + xoct * 8];
    } else {
      #pragma unroll
      for (int i = 0; i < 4; ++i)
        af[i] = *(const bf16x8*)&As[(wm + i * 16 + lm) * 40 + quad * 8];
    }
    #pragma unroll
    for (int j = 0; j < 4; ++j) bfv[j] = *(const bf16x8*)&Bs[wn + j * 16 + lm][quad * 8];
    #pragma unroll
    for (int i = 0; i < 4; ++i)
      #pragma unroll
      for (int j = 0; j < 4; ++j)
        acc[i][j] = __builtin_amdgcn_mfma_f32_16x16x32_bf16(af[i], bfv[j], acc[i][j], 0, 0, 0);
  }

  // -- epilogue: D row = quad*4 + r, col = lm --
  float* outb = out + ((size_t)b * COUT + m0) * NPIX;
  #pragma unroll
  for (int j = 0; j < 4; ++j) {
    const int p = p0 + wn + j * 16 + lm;
    if (p < NPIX) {
      #pragma unroll
      for (int i = 0; i < 4; ++i) {
        #pragma unroll
        for (int r = 0; r < 4; ++r) {
          const int m = wm + i * 16 + quad * 4 + r;
          outb[(size_t)m * NPIX + p] = acc[i][j][r] + biasS[m];
        }
      }
    }
  }
}

extern "C" void kernel_launch(void* const* d_in, const int* in_sizes, int n_in,
                              void* d_out, int out_size, void* d_ws, size_t ws_size,
                              hipStream_t stream) {
  (void)in_sizes; (void)n_in; (void)out_size;
  const float* x  = (const float*)d_in[0];
  const float* wc = (const float*)d_in[1];
  const float* bc = (const float*)d_in[2];
  const float* we = (const float*)d_in[3];
  const float* be = (const float*)d_in[4];
  const float* w1 = (const float*)d_in[5];
  const float* w2 = (const float*)d_in[6];
  float* out = (float*)d_out;

  float* att    = (float*)d_ws;    // 256 floats
  float* pooled = att + 256;       // 12288 floats (ends < 64KB)
  unsigned* aggW = (unsigned*)((char*)d_ws + AGG_OFF);

  pool_kernel<<<dim3(CIN, NB), 256, 0, stream>>>(x, pooled);
  attn_kernel<<<NB, 64, 0, stream>>>(pooled, w1, w2, att);

  if (ws_size >= AGG_OFF + AGG_BYTES) {
    agg_kernel<<<dim3(KSTEPS, 2, NB), 256, 0, stream>>>(wc, we, att, aggW);
    conv_kernel<true><<<dim3(8, 2, NB), 256, 0, stream>>>(x, wc, we, bc, be, att, aggW, out);
  } else {
    conv_kernel<false><<<dim3(8, 2, NB), 256, 0, stream>>>(x, wc, we, bc, be, att, aggW, out);
  }
}

// Round 2
// 745.859 us; speedup vs baseline: 1.1151x; 1.0492x over previous
//
#include <hip/hip_runtime.h>
#include <math.h>

#define CIN   96
#define HW_IN 3969     // 63*63
#define WIN   63
#define COUT  256
#define NPIX  900      // 30*30
#define WO    30
#define KTOT  2400     // CIN*5*5
#define NB    128
#define KSTEPS 75      // KTOT/32
#define AGG_OFF 65536
#define AGG_BYTES ((size_t)NB * 2 * KSTEPS * 8192)   // 157,286,400 B

typedef short bf16x8 __attribute__((ext_vector_type(8)));
typedef float f32x4  __attribute__((ext_vector_type(4)));
typedef __attribute__((address_space(1))) const void gas_t;
typedef __attribute__((address_space(3))) void las_t;

// hardware packed f32->bf16 (RNE), 2 values per instruction
__device__ __forceinline__ unsigned pk2(float lo, float hi) {
  unsigned r;
  asm("v_cvt_pk_bf16_f32 %0, %1, %2" : "=v"(r) : "v"(lo), "v"(hi));
  return r;
}

// ---- Stage 1: per-(b,ci) global average pool over 63x63 ----
__global__ __launch_bounds__(256) void pool_kernel(const float* __restrict__ x,
                                                   float* __restrict__ pooled) {
  const int ci = blockIdx.x;
  const int b  = blockIdx.y;
  const float* xc = x + ((size_t)b * CIN + ci) * HW_IN;
  const int tid = threadIdx.x, lane = tid & 63, wv = tid >> 6;
  float s = 0.f;
  const int head = (4 - (ci & 3)) & 3;
  if (tid < head) s += xc[tid];
  const float4* x4 = (const float4*)(xc + head);
  const int n4 = (HW_IN - head) >> 2;
  for (int i = tid; i < n4; i += 256) { float4 v = x4[i]; s += (v.x + v.y) + (v.z + v.w); }
  const int done = head + (n4 << 2);
  if (tid < HW_IN - done) s += xc[done + tid];
  #pragma unroll
  for (int off = 32; off > 0; off >>= 1) s += __shfl_xor(s, off, 64);
  __shared__ float part[4];
  if (lane == 0) part[wv] = s;
  __syncthreads();
  if (tid == 0)
    pooled[(size_t)b * CIN + ci] = (part[0] + part[1] + part[2] + part[3]) * (1.0f / HW_IN);
}

// ---- Stage 2: attention MLP + softmax(logits / 31) ----
__global__ __launch_bounds__(64) void attn_kernel(const float* __restrict__ pooled,
                                                  const float* __restrict__ w1,
                                                  const float* __restrict__ w2,
                                                  float* __restrict__ att) {
  const int b = blockIdx.x;
  const int tid = threadIdx.x;
  __shared__ float hidden[24];
  const float* pb = pooled + (size_t)b * CIN;
  if (tid < 24) {
    float h = 0.f;
    const float* w1r = w1 + tid * CIN;
    for (int ci = 0; ci < CIN; ++ci) h += pb[ci] * w1r[ci];
    hidden[tid] = fmaxf(h, 0.f);
  }
  __syncthreads();
  if (tid == 0) {
    float l0 = 0.f, l1 = 0.f;
    for (int j = 0; j < 24; ++j) { l0 += hidden[j] * w2[j]; l1 += hidden[j] * w2[24 + j]; }
    l0 *= (1.0f / 31.0f); l1 *= (1.0f / 31.0f);
    const float m = fmaxf(l0, l1);
    const float e0 = expf(l0 - m), e1 = expf(l1 - m);
    const float inv = 1.0f / (e0 + e1);
    att[b * 2 + 0] = e0 * inv;
    att[b * 2 + 1] = e1 * inv;
  }
}

// ---- Stage 2.5: precompute per-sample aggregated bf16 weights ----
// Layout (matches conv's global_load_lds image exactly):
//   tile (b, t, ks) = contiguous 8192 B = [row 0..127][slot 0..3] 16B units.
//   unit (row, slot) = bf16x8 of A[t*128+row][ks*32 + 8*(slot ^ ((row>>1)&3)) + 0..7]
__global__ __launch_bounds__(256) void agg_kernel(const float* __restrict__ wc,
                                                  const float* __restrict__ we,
                                                  const float* __restrict__ att,
                                                  unsigned* __restrict__ aggW) {
  const int ks = blockIdx.x;   // 75
  const int t  = blockIdx.y;   // 2
  const int b  = blockIdx.z;   // 128
  const float a0 = att[b * 2 + 0];
  const float a1 = att[b * 2 + 1];
  unsigned* dst = aggW + ((size_t)((b * 2 + t) * KSTEPS + ks) << 11);  // 2048 dwords/tile
  #pragma unroll
  for (int uu = 0; uu < 2; ++uu) {
    const int u = threadIdx.x + uu * 256;          // 0..511 (16B units)
    const int row = u >> 2, slot = u & 3;
    const int oct = slot ^ ((row >> 1) & 3);
    const float* pc = wc + (size_t)(t * 128 + row) * KTOT + ks * 32 + oct * 8;
    const float* pe = we + (size_t)(t * 128 + row) * KTOT + ks * 32 + oct * 8;
    float4 c0 = ((const float4*)pc)[0], c1 = ((const float4*)pc)[1];
    float4 e0 = ((const float4*)pe)[0], e1 = ((const float4*)pe)[1];
    uint4 q;
    q.x = pk2(a0 * c0.x + a1 * e0.x, a0 * c0.y + a1 * e0.y);
    q.y = pk2(a0 * c0.z + a1 * e0.z, a0 * c0.w + a1 * e0.w);
    q.z = pk2(a0 * c1.x + a1 * e1.x, a0 * c1.y + a1 * e1.y);
    q.w = pk2(a0 * c1.z + a1 * e1.z, a0 * c1.w + a1 * e1.w);
    ((uint4*)dst)[u] = q;
  }
}

// ---- Stage 3: per-sample conv as implicit GEMM, 2-phase pipelined ----
// One barrier per K-step; stage(t+1) issued before compute(t); dbuf LDS.
__global__ __launch_bounds__(256) void conv_pre(
    const float* __restrict__ x,
    const float* __restrict__ bc, const float* __restrict__ be,
    const float* __restrict__ att, const unsigned* __restrict__ aggW,
    float* __restrict__ out) {
  // bijective XCD swizzle over 2048 workgroups
  const int flat = (int)(blockIdx.x + (blockIdx.y << 3) + (blockIdx.z << 4));
  const int wg   = ((flat & 7) << 8) | (flat >> 3);
  const int p0 = (wg & 7) * 128;          // pixel tile
  const int m0 = ((wg >> 3) & 1) * 128;   // Cout tile
  const int b  = wg >> 4;                 // sample

  __shared__ short As[2][128 * 32];       // linear, XOR-swizzled slots (gl_lds image)
  __shared__ short Bs[2][128][40];        // [n][k], +8 pad
  __shared__ int   koffAll[KTOT];
  __shared__ float biasS[128];

  const int tid  = threadIdx.x;
  const int wv   = tid >> 6, lane = tid & 63;
  const int quad = lane >> 4, lm = lane & 15;
  const int wm = (wv >> 1) * 64;
  const int wn = (wv & 1) * 64;

  if (tid < 128) {
    const float a0 = att[b * 2 + 0], a1 = att[b * 2 + 1];
    biasS[tid] = a0 * bc[m0 + tid] + a1 * be[m0 + tid];
  }
  for (int k = tid; k < KTOT; k += 256) {
    const int ci = k / 25, r = k - ci * 25;
    const int kh = r / 5,  kw = r - kh * 5;
    koffAll[k] = ci * HW_IN + kh * WIN + kw;
  }

  const int rowT = tid >> 2;
  const int oct  = (tid & 3) * 8;

  const float* xb = x + (size_t)b * (CIN * HW_IN);
  const int pA = p0 + rowT, pB = p0 + rowT + 64;
  const int ohA = pA / WO, owA = pA - ohA * WO;
  const int ohB = pB / WO, owB = pB - ohB * WO;
  const bool vA = pA < NPIX, vB = pB < NPIX;
  const float* xpA = xb + (ohA * 2) * WIN + owA * 2;
  const float* xpB = xb + (ohB * 2) * WIN + owB * 2;

  const char* aggB = (const char*)aggW
                   + ((size_t)((b * 2 + (m0 >> 7)) * KSTEPS) << 13)
                   + (((wv << 7) + lane) << 4);
  const int xoct = quad ^ ((lm >> 1) & 3);   // un-swizzle for fragment reads

  const f32x4 zero = {0.f, 0.f, 0.f, 0.f};
  f32x4 acc[4][4];
  #pragma unroll
  for (int i = 0; i < 4; ++i)
    #pragma unroll
    for (int j = 0; j < 4; ++j) acc[i][j] = zero;

  __syncthreads();   // koffAll / biasS ready

  // --- prologue: stage tile 0 into buffer 0 ---
  {
    __builtin_amdgcn_global_load_lds((gas_t*)aggB, (las_t*)&As[0][wv << 10], 16, 0, 0);
    __builtin_amdgcn_global_load_lds((gas_t*)(aggB + 1024), (las_t*)&As[0][(wv << 10) + 512], 16, 0, 0);
    const int4 ka = *(const int4*)&koffAll[oct];
    const int4 kb = *(const int4*)&koffAll[oct + 4];
    uint4 qa = {0u, 0u, 0u, 0u}, qb = {0u, 0u, 0u, 0u};
    if (vA) {
      qa.x = pk2(xpA[ka.x], xpA[ka.y]); qa.y = pk2(xpA[ka.z], xpA[ka.w]);
      qa.z = pk2(xpA[kb.x], xpA[kb.y]); qa.w = pk2(xpA[kb.z], xpA[kb.w]);
    }
    if (vB) {
      qb.x = pk2(xpB[ka.x], xpB[ka.y]); qb.y = pk2(xpB[ka.z], xpB[ka.w]);
      qb.z = pk2(xpB[kb.x], xpB[kb.y]); qb.w = pk2(xpB[kb.z], xpB[kb.w]);
    }
    *(uint4*)&Bs[0][rowT][oct] = qa;
    *(uint4*)&Bs[0][rowT + 64][oct] = qb;
  }
  __syncthreads();   // tile 0 resident (implicit vmcnt(0) drains gl_lds)

  int cur = 0;
  for (int ks = 0; ks < KSTEPS - 1; ++ks) {
    const int nxt = cur ^ 1;
    // -- issue stage(t+1): A direct-to-LDS + B gathers to regs --
    const char* src = aggB + ((size_t)(ks + 1) << 13);
    __builtin_amdgcn_global_load_lds((gas_t*)src, (las_t*)&As[nxt][wv << 10], 16, 0, 0);
    __builtin_amdgcn_global_load_lds((gas_t*)(src + 1024), (las_t*)&As[nxt][(wv << 10) + 512], 16, 0, 0);
    const int k0n = (ks + 1) * 32;
    const int4 ka = *(const int4*)&koffAll[k0n + oct];
    const int4 kb = *(const int4*)&koffAll[k0n + oct + 4];
    float g0 = 0.f, g1 = 0.f, g2 = 0.f, g3 = 0.f, g4 = 0.f, g5 = 0.f, g6 = 0.f, g7 = 0.f;
    float h0 = 0.f, h1 = 0.f, h2 = 0.f, h3 = 0.f, h4 = 0.f, h5 = 0.f, h6 = 0.f, h7 = 0.f;
    if (vA) {
      g0 = xpA[ka.x]; g1 = xpA[ka.y]; g2 = xpA[ka.z]; g3 = xpA[ka.w];
      g4 = xpA[kb.x]; g5 = xpA[kb.y]; g6 = xpA[kb.z]; g7 = xpA[kb.w];
    }
    if (vB) {
      h0 = xpB[ka.x]; h1 = xpB[ka.y]; h2 = xpB[ka.z]; h3 = xpB[ka.w];
      h4 = xpB[kb.x]; h5 = xpB[kb.y]; h6 = xpB[kb.z]; h7 = xpB[kb.w];
    }
    // -- compute(t) on buffer cur: latency of the above hides under this --
    bf16x8 af[4], bfv[4];
    #pragma unroll
    for (int i = 0; i < 4; ++i)
      af[i] = *(const bf16x8*)&As[cur][(wm + i * 16 + lm) * 32 + xoct * 8];
    #pragma unroll
    for (int j = 0; j < 4; ++j)
      bfv[j] = *(const bf16x8*)&Bs[cur][wn + j * 16 + lm][quad * 8];
    #pragma unroll
    for (int i = 0; i < 4; ++i)
      #pragma unroll
      for (int j = 0; j < 4; ++j)
        acc[i][j] = __builtin_amdgcn_mfma_f32_16x16x32_bf16(af[i], bfv[j], acc[i][j], 0, 0, 0);
    // -- write stage(t+1) B to LDS (waits on gathers only now) --
    uint4 qa, qb;
    qa.x = pk2(g0, g1); qa.y = pk2(g2, g3); qa.z = pk2(g4, g5); qa.w = pk2(g6, g7);
    qb.x = pk2(h0, h1); qb.y = pk2(h2, h3); qb.z = pk2(h4, h5); qb.w = pk2(h6, h7);
    *(uint4*)&Bs[nxt][rowT][oct] = qa;
    *(uint4*)&Bs[nxt][rowT + 64][oct] = qb;
    __syncthreads();   // drains gl_lds (vmcnt 0) + publishes Bs[nxt]
    cur = nxt;
  }

  // --- epilogue: compute last tile ---
  {
    bf16x8 af[4], bfv[4];
    #pragma unroll
    for (int i = 0; i < 4; ++i)
      af[i] = *(const bf16x8*)&As[cur][(wm + i * 16 + lm) * 32 + xoct * 8];
    #pragma unroll
    for (int j = 0; j < 4; ++j)
      bfv[j] = *(const bf16x8*)&Bs[cur][wn + j * 16 + lm][quad * 8];
    #pragma unroll
    for (int i = 0; i < 4; ++i)
      #pragma unroll
      for (int j = 0; j < 4; ++j)
        acc[i][j] = __builtin_amdgcn_mfma_f32_16x16x32_bf16(af[i], bfv[j], acc[i][j], 0, 0, 0);
  }

  // -- store: D row = quad*4 + r, col = lm --
  float* outb = out + ((size_t)b * COUT + m0) * NPIX;
  #pragma unroll
  for (int j = 0; j < 4; ++j) {
    const int p = p0 + wn + j * 16 + lm;
    if (p < NPIX) {
      #pragma unroll
      for (int i = 0; i < 4; ++i) {
        #pragma unroll
        for (int r = 0; r < 4; ++r) {
          const int m = wm + i * 16 + quad * 4 + r;
          outb[(size_t)m * NPIX + p] = acc[i][j][r] + biasS[m];
        }
      }
    }
  }
}

// ---- fallback (workspace too small): in-kernel aggregation, 2-barrier loop ----
__global__ __launch_bounds__(256) void conv_fb(
    const float* __restrict__ x,
    const float* __restrict__ wc, const float* __restrict__ we,
    const float* __restrict__ bc, const float* __restrict__ be,
    const float* __restrict__ att, float* __restrict__ out) {
  const int flat = (int)(blockIdx.x + (blockIdx.y << 3) + (blockIdx.z << 4));
  const int wg   = ((flat & 7) << 8) | (flat >> 3);
  const int p0 = (wg & 7) * 128;
  const int m0 = ((wg >> 3) & 1) * 128;
  const int b  = wg >> 4;

  __shared__ short As[128 * 40];
  __shared__ short Bs[128][40];
  __shared__ int   koffAll[KTOT];
  __shared__ float biasS[128];

  const int tid  = threadIdx.x;
  const int wv   = tid >> 6, lane = tid & 63;
  const int quad = lane >> 4, lm = lane & 15;
  const int wm = (wv >> 1) * 64;
  const int wn = (wv & 1) * 64;

  const float a0 = att[b * 2 + 0];
  const float a1 = att[b * 2 + 1];

  if (tid < 128) biasS[tid] = a0 * bc[m0 + tid] + a1 * be[m0 + tid];
  for (int k = tid; k < KTOT; k += 256) {
    const int ci = k / 25, r = k - ci * 25;
    const int kh = r / 5,  kw = r - kh * 5;
    koffAll[k] = ci * HW_IN + kh * WIN + kw;
  }

  const int rowT = tid >> 2;
  const int oct  = (tid & 3) * 8;

  const float* xb = x + (size_t)b * (CIN * HW_IN);
  const int pA = p0 + rowT, pB = p0 + rowT + 64;
  const int ohA = pA / WO, owA = pA - ohA * WO;
  const int ohB = pB / WO, owB = pB - ohB * WO;
  const bool vA = pA < NPIX, vB = pB < NPIX;
  const float* xpA = xb + (ohA * 2) * WIN + owA * 2;
  const float* xpB = xb + (ohB * 2) * WIN + owB * 2;

  const float* wcr0 = wc + (size_t)(m0 + rowT) * KTOT + oct;
  const float* wer0 = we + (size_t)(m0 + rowT) * KTOT + oct;

  const f32x4 zero = {0.f, 0.f, 0.f, 0.f};
  f32x4 acc[4][4];
  #pragma unroll
  for (int i = 0; i < 4; ++i)
    #pragma unroll
    for (int j = 0; j < 4; ++j) acc[i][j] = zero;

  for (int k0 = 0; k0 < KTOT; k0 += 32) {
    __syncthreads();
    #pragma unroll
    for (int t = 0; t < 2; ++t) {
      const float4* pc = (const float4*)(wcr0 + (size_t)t * 64 * KTOT + k0);
      const float4* pe = (const float4*)(wer0 + (size_t)t * 64 * KTOT + k0);
      float4 c0 = pc[0], c1 = pc[1];
      float4 e0 = pe[0], e1 = pe[1];
      uint4 q;
      q.x = pk2(a0 * c0.x + a1 * e0.x, a0 * c0.y + a1 * e0.y);
      q.y = pk2(a0 * c0.z + a1 * e0.z, a0 * c0.w + a1 * e0.w);
      q.z = pk2(a0 * c1.x + a1 * e1.x, a0 * c1.y + a1 * e1.y);
      q.w = pk2(a0 * c1.z + a1 * e1.z, a0 * c1.w + a1 * e1.w);
      *(uint4*)&As[(rowT + t * 64) * 40 + oct] = q;
    }
    const int4 ka = *(const int4*)&koffAll[k0 + oct];
    const int4 kb = *(const int4*)&koffAll[k0 + oct + 4];
    {
      uint4 q = {0u, 0u, 0u, 0u};
      if (vA) {
        q.x = pk2(xpA[ka.x], xpA[ka.y]); q.y = pk2(xpA[ka.z], xpA[ka.w]);
        q.z = pk2(xpA[kb.x], xpA[kb.y]); q.w = pk2(xpA[kb.z], xpA[kb.w]);
      }
      *(uint4*)&Bs[rowT][oct] = q;
    }
    {
      uint4 q = {0u, 0u, 0u, 0u};
      if (vB) {
        q.x = pk2(xpB[ka.x], xpB[ka.y]); q.y = pk2(xpB[ka.z], xpB[ka.w]);
        q.z = pk2(xpB[kb.x], xpB[kb.y]); q.w = pk2(xpB[kb.z], xpB[kb.w]);
      }
      *(uint4*)&Bs[rowT + 64][oct] = q;
    }
    __syncthreads();
    bf16x8 af[4], bfv[4];
    #pragma unroll
    for (int i = 0; i < 4; ++i) af[i]  = *(const bf16x8*)&As[(wm + i * 16 + lm) * 40 + quad * 8];
    #pragma unroll
    for (int j = 0; j < 4; ++j) bfv[j] = *(const bf16x8*)&Bs[wn + j * 16 + lm][quad * 8];
    #pragma unroll
    for (int i = 0; i < 4; ++i)
      #pragma unroll
      for (int j = 0; j < 4; ++j)
        acc[i][j] = __builtin_amdgcn_mfma_f32_16x16x32_bf16(af[i], bfv[j], acc[i][j], 0, 0, 0);
  }

  float* outb = out + ((size_t)b * COUT + m0) * NPIX;
  #pragma unroll
  for (int j = 0; j < 4; ++j) {
    const int p = p0 + wn + j * 16 + lm;
    if (p < NPIX) {
      #pragma unroll
      for (int i = 0; i < 4; ++i) {
        #pragma unroll
        for (int r = 0; r < 4; ++r) {
          const int m = wm + i * 16 + quad * 4 + r;
          outb[(size_t)m * NPIX + p] = acc[i][j][r] + biasS[m];
        }
      }
    }
  }
}

extern "C" void kernel_launch(void* const* d_in, const int* in_sizes, int n_in,
                              void* d_out, int out_size, void* d_ws, size_t ws_size,
                              hipStream_t stream) {
  (void)in_sizes; (void)n_in; (void)out_size;
  const float* x  = (const float*)d_in[0];
  const float* wc = (const float*)d_in[1];
  const float* bc = (const float*)d_in[2];
  const float* we = (const float*)d_in[3];
  const float* be = (const float*)d_in[4];
  const float* w1 = (const float*)d_in[5];
  const float* w2 = (const float*)d_in[6];
  float* out = (float*)d_out;

  float* att    = (float*)d_ws;    // 256 floats
  float* pooled = att + 256;       // 12288 floats (ends < 64KB)
  unsigned* aggW = (unsigned*)((char*)d_ws + AGG_OFF);

  pool_kernel<<<dim3(CIN, NB), 256, 0, stream>>>(x, pooled);
  attn_kernel<<<NB, 64, 0, stream>>>(pooled, w1, w2, att);

  if (ws_size >= AGG_OFF + AGG_BYTES) {
    agg_kernel<<<dim3(KSTEPS, 2, NB), 256, 0, stream>>>(wc, we, att, aggW);
    conv_pre<<<dim3(8, 2, NB), 256, 0, stream>>>(x, bc, be, att, aggW, out);
  } else {
    conv_fb<<<dim3(8, 2, NB), 256, 0, stream>>>(x, wc, we, bc, be, att, out);
  }
}